// Round 4
// baseline (95.951 us; speedup 1.0000x reference)
//
#include <hip/hip_runtime.h>
#include <float.h>

#define NB 8
#define NC 64
#define NH 32
#define NW 32
#define NQ 8
#define NK 256
#define NROWS (NB*NC*NH*NW)      // 524288
#define TPB 256
#define NBLK (NROWS/TPB)         // 2048
#define BIT_OFF 1
#define REC_OFF (1 + NROWS*NQ)

// ws layout (bytes):
//  g_breaks: double[64][256]     @ 0        (128 KiB)  segment start (i>=1)
//  g_win:    int   [64][256]     @ 131072   ( 64 KiB)  winner code per segment
//  g_segcb:  float [64][256][8]  @ 196608   (512 KiB)  codebook row per segment
//  g_segR:   float [64][256]     @ 720896   ( 64 KiB)  recon value per segment
//  g_segBG:  double[64][256][2]  @ 786432   (256 KiB)  {beta, gamma} per segment
//  g_alpha:  double[64]          @ 1048576
//  g_m:      int[64]             @ 1049088
//  g_cnt:    unsigned            @ 1049600
//  partial:  double[2048]        @ 1049856  (16 KiB)
#define WS_BREAKS(ws) ((double*)(ws))
#define WS_WIN(ws)    ((int*)((char*)(ws) + 131072))
#define WS_SEGCB(ws)  ((float*)((char*)(ws) + 196608))
#define WS_SEGR(ws)   ((float*)((char*)(ws) + 720896))
#define WS_SEGBG(ws)  ((double*)((char*)(ws) + 786432))
#define WS_ALPHA(ws)  ((double*)((char*)(ws) + 1048576))
#define WS_M(ws)      ((int*)((char*)(ws) + 1049088))
#define WS_CNT(ws)    ((unsigned*)((char*)(ws) + 1049600))
#define WS_PART(ws)   ((double*)((char*)(ws) + 1049856))

// ---------------------------------------------------------------------------
// Kernel A: one wave per channel. Lower envelope of d_k(x) = P[k] + x*S[k],
// then materialize per-segment payload. Register-only (no LDS, no barriers).
// Reduce semantics identical to the verified R3 kernel (lex 3-key, f64 div).
// ---------------------------------------------------------------------------
__global__ __launch_bounds__(64) void vq_envelope(
    const float* __restrict__ w_pre,
    const float* __restrict__ b_pre,
    const float* __restrict__ codebook,
    const float* __restrict__ w_after,
    const float* __restrict__ b_after,
    double* __restrict__ g_breaks,
    int* __restrict__ g_win,
    float* __restrict__ g_segcb,
    float* __restrict__ g_segR,
    double* __restrict__ g_segBG,
    double* __restrict__ g_alpha,
    int* __restrict__ g_m,
    unsigned* __restrict__ g_cnt)
{
    const int c = blockIdx.x;
    const int lane = threadIdx.x;
    if (c == 0 && lane == 0) *g_cnt = 0u;   // reset fused-fin counter each call

    // per-channel uniform weights + kl quadratic constants
    double wp[NQ], bp[NQ], wa[NQ];
    double sw2 = 0.0, swb = 0.0, sb2 = 0.0;
    #pragma unroll
    for (int q = 0; q < NQ; q++) {
        wp[q] = (double)w_pre[c*NQ + q];
        bp[q] = (double)b_pre[c*NQ + q];
        wa[q] = (double)w_after[c*NQ + q];
        sw2 = fma(wp[q], wp[q], sw2);
        swb = fma(wp[q], bp[q], swb);
        sb2 = fma(bp[q], bp[q], sb2);
    }
    const double ba = (double)b_after[c];

    // P,S for the 4 codes this lane owns: k = 4*lane + i
    double P[4], S[4];
    #pragma unroll
    for (int i = 0; i < 4; i++) {
        const int k = 4*lane + i;
        double c2 = 0.0, A = 0.0, Bv = 0.0;
        #pragma unroll
        for (int q = 0; q < NQ; q++) {
            double cv = (double)codebook[k*NQ + q];
            c2 = fma(cv, cv, c2);
            A  = fma(wp[q], cv, A);
            Bv = fma(bp[q], cv, Bv);
        }
        P[i] = c2 - 2.0*Bv;
        S[i] = -2.0*A;
    }

    // initial winner at x=-inf: max S, tie min P, tie min k
    double bs = S[0], bP = P[0];
    int bk = 4*lane;
    #pragma unroll
    for (int i = 1; i < 4; i++) {
        const int k = 4*lane + i;
        if (S[i] > bs || (S[i] == bs && (P[i] < bP || (P[i] == bP && k < bk)))) {
            bs = S[i]; bP = P[i]; bk = k;
        }
    }
    #pragma unroll
    for (int off = 32; off; off >>= 1) {
        double os = __shfl_xor(bs, off, 64);
        double oP = __shfl_xor(bP, off, 64);
        int    ok = __shfl_xor(bk, off, 64);
        if (os > bs || (os == bs && (oP < bP || (oP == bP && ok < bk)))) {
            bs = os; bP = oP; bk = ok;
        }
    }
    int cur = bk;                       // all lanes agree
    if (lane == 0) g_win[c*NK + 0] = cur;
    int m = 1;

    // envelope walk
    while (m < NK) {
        const int owner = cur >> 2, slot = cur & 3;   // slot is wave-uniform
        double Si, Pi;
        { double t0 = S[0], t1 = S[1], t2 = S[2], t3 = S[3];
          double v = (slot == 0) ? t0 : (slot == 1) ? t1 : (slot == 2) ? t2 : t3;
          Si = __shfl(v, owner, 64); }
        { double t0 = P[0], t1 = P[1], t2 = P[2], t3 = P[3];
          double v = (slot == 0) ? t0 : (slot == 1) ? t1 : (slot == 2) ? t2 : t3;
          Pi = __shfl(v, owner, 64); }

        double cx = DBL_MAX, cs = 0.0;
        int cj = NK;
        #pragma unroll
        for (int i = 0; i < 4; i++) {
            const int k = 4*lane + i;
            if (S[i] < Si) {
                double t = (P[i] - Pi) / (Si - S[i]);
                if (t < cx || (t == cx && (S[i] < cs || (S[i] == cs && k < cj)))) {
                    cx = t; cs = S[i]; cj = k;
                }
            }
        }
        #pragma unroll
        for (int off = 32; off; off >>= 1) {
            double ox = __shfl_xor(cx, off, 64);
            double os = __shfl_xor(cs, off, 64);
            int    oj = __shfl_xor(cj, off, 64);
            if (ox < cx || (ox == cx && (os < cs || (os == cs && oj < cj)))) {
                cx = ox; cs = os; cj = oj;
            }
        }
        if (cx == DBL_MAX) break;       // nothing ever overtakes
        if (lane == 0) {
            g_breaks[c*NK + m] = cx;
            g_win[c*NK + m]    = cj;
        }
        cur = cj;
        m++;
    }
    if (lane == 0) {
        g_m[c] = m;
        g_alpha[c] = sw2;
    }
    __threadfence();   // make lane0's g_win stores visible before payload reads

    // payload: seg i -> {cb row, R, beta, gamma}
    for (int i = lane; i < m; i += 64) {
        const int j = g_win[c*NK + i];
        double c2 = 0.0, A = 0.0, Bv = 0.0, R = ba;
        #pragma unroll
        for (int q = 0; q < NQ; q++) {
            float cf = codebook[j*NQ + q];
            g_segcb[(c*NK + i)*NQ + q] = cf;
            double cv = (double)cf;
            c2 = fma(cv, cv, c2);
            A  = fma(wp[q], cv, A);
            Bv = fma(bp[q], cv, Bv);
            R  = fma(wa[q], cv, R);      // same fma order as the verified kernel
        }
        const double Pj = c2 - 2.0*Bv;
        const double Sj = -2.0*A;
        g_segR[c*NK + i] = (float)R;
        g_segBG[(c*NK + i)*2 + 0] = Sj + 2.0*swb;   // beta
        g_segBG[(c*NK + i)*2 + 1] = Pj + sb2;       // gamma
    }
}

// ---------------------------------------------------------------------------
// Kernel B: per-row binary search + outputs + fused kl finalization
// ---------------------------------------------------------------------------
__global__ __launch_bounds__(TPB) void vq_main(
    const float* __restrict__ x,
    const double* __restrict__ g_breaks,
    const float* __restrict__ g_segcb,
    const float* __restrict__ g_segR,
    const double* __restrict__ g_segBG,
    const double* __restrict__ g_alpha,
    const int* __restrict__ g_m,
    unsigned* __restrict__ g_cnt,
    float* __restrict__ out,
    double* __restrict__ partial)
{
    __shared__ double s_brk[NK];
    __shared__ float  s_cb[NK][9];     // stride 9: conflict-free scatter reads
    __shared__ float  s_R[NK];
    __shared__ double s_bg[NK][2];
    __shared__ double s_alpha;
    __shared__ double s_part[TPB/64];
    __shared__ int    s_flag;

    const int tid = threadIdx.x;
    const int gid = blockIdx.x * TPB + tid;
    const int c  = (gid >> 10) & 63;   // block-uniform
    const int b  = gid >> 16;
    const int hw = gid & 1023;

    const int m = g_m[c];
    if (tid == 0) s_alpha = g_alpha[c];
    if (tid < m) {
        s_brk[tid] = (tid == 0) ? -DBL_MAX : g_breaks[c*NK + tid];
        #pragma unroll
        for (int q = 0; q < NQ; q++)
            s_cb[tid][q] = g_segcb[(c*NK + tid)*NQ + q];
        s_R[tid] = g_segR[c*NK + tid];
        s_bg[tid][0] = g_segBG[(c*NK + tid)*2 + 0];
        s_bg[tid][1] = g_segBG[(c*NK + tid)*2 + 1];
    }
    __syncthreads();

    const double xv = (double)x[gid];

    // largest seg with s_brk[seg] <= xv
    int lo = 0, hi = m - 1;
    while (lo < hi) {
        int mid = (lo + hi + 1) >> 1;
        if (s_brk[mid] <= xv) lo = mid; else hi = mid - 1;
    }

    const int bq = BIT_OFF + (b*512 + c*8)*1024 + hw;
    #pragma unroll
    for (int q = 0; q < NQ; q++)
        out[bq + q*1024] = s_cb[lo][q];
    out[REC_OFF + gid] = s_R[lo];

    double ksum = fma(xv, fma(xv, s_alpha, s_bg[lo][0]), s_bg[lo][1]);

    #pragma unroll
    for (int off = 32; off; off >>= 1)
        ksum += __shfl_down(ksum, off, 64);
    if ((tid & 63) == 0) s_part[tid >> 6] = ksum;
    __syncthreads();
    if (tid == 0) {
        partial[blockIdx.x] = s_part[0] + s_part[1] + s_part[2] + s_part[3];
        __threadfence();
        unsigned old = atomicAdd(g_cnt, 1u);
        s_flag = (old == NBLK - 1) ? 1 : 0;
    }
    __syncthreads();
    if (s_flag) {                       // last block finalizes kl
        __threadfence();
        double s = 0.0;
        for (int i = tid; i < NBLK; i += TPB) s += partial[i];
        #pragma unroll
        for (int off = 32; off; off >>= 1)
            s += __shfl_down(s, off, 64);
        __syncthreads();
        if ((tid & 63) == 0) s_part[tid >> 6] = s;
        __syncthreads();
        if (tid == 0) {
            double mean = (s_part[0] + s_part[1] + s_part[2] + s_part[3])
                          / (double)(NROWS * NQ);
            out[0] = (float)(1.25 * mean);
        }
    }
}

extern "C" void kernel_launch(void* const* d_in, const int* in_sizes, int n_in,
                              void* d_out, int out_size, void* d_ws, size_t ws_size,
                              hipStream_t stream) {
    const float* x        = (const float*)d_in[0];
    const float* w_pre    = (const float*)d_in[1];
    const float* b_pre    = (const float*)d_in[2];
    const float* codebook = (const float*)d_in[3];
    const float* w_after  = (const float*)d_in[4];
    const float* b_after  = (const float*)d_in[5];
    float* out = (float*)d_out;

    vq_envelope<<<NC, 64, 0, stream>>>(w_pre, b_pre, codebook, w_after, b_after,
                                       WS_BREAKS(d_ws), WS_WIN(d_ws), WS_SEGCB(d_ws),
                                       WS_SEGR(d_ws), WS_SEGBG(d_ws), WS_ALPHA(d_ws),
                                       WS_M(d_ws), WS_CNT(d_ws));
    vq_main<<<NBLK, TPB, 0, stream>>>(x, WS_BREAKS(d_ws), WS_SEGCB(d_ws),
                                      WS_SEGR(d_ws), WS_SEGBG(d_ws), WS_ALPHA(d_ws),
                                      WS_M(d_ws), WS_CNT(d_ws), out, WS_PART(d_ws));
}

// Round 5
// 30.431 us; speedup vs baseline: 3.1531x; 3.1531x over previous
//
#include <hip/hip_runtime.h>
#include <float.h>

#define NB 8
#define NC 64
#define NH 32
#define NW 32
#define NQ 8
#define NK 256
#define NROWS (NB*NC*NH*NW)      // 524288
#define TPB 256
#define NBLK (NROWS/TPB)         // 2048
#define BIT_OFF 1
#define REC_OFF (1 + NROWS*NQ)

// ws layout (bytes):
//  g_breaks: double[64][256]     @ 0        (128 KiB)
//  g_win:    int   [64][256]     @ 131072   ( 64 KiB)
//  g_segcb:  float [64][256][8]  @ 196608   (512 KiB)
//  g_segR:   float [64][256]     @ 720896   ( 64 KiB)
//  g_segBG:  double[64][256][2]  @ 786432   (256 KiB)
//  g_alpha:  double[64]          @ 1048576
//  g_m:      int[64]             @ 1049088
//  partial:  double[2048]        @ 1049856  (16 KiB)
#define WS_BREAKS(ws) ((double*)(ws))
#define WS_WIN(ws)    ((int*)((char*)(ws) + 131072))
#define WS_SEGCB(ws)  ((float*)((char*)(ws) + 196608))
#define WS_SEGR(ws)   ((float*)((char*)(ws) + 720896))
#define WS_SEGBG(ws)  ((double*)((char*)(ws) + 786432))
#define WS_ALPHA(ws)  ((double*)((char*)(ws) + 1048576))
#define WS_M(ws)      ((int*)((char*)(ws) + 1049088))
#define WS_PART(ws)   ((double*)((char*)(ws) + 1049856))

// ---------------------------------------------------------------------------
// Kernel A: one wave per channel; lower envelope of d_k(x) = P[k] + x*S[k];
// per-segment payload {break, cb row, R, beta, gamma}. Same f64 semantics as
// the verified R3/R4 kernels.
// ---------------------------------------------------------------------------
__global__ __launch_bounds__(64) void vq_envelope(
    const float* __restrict__ w_pre,
    const float* __restrict__ b_pre,
    const float* __restrict__ codebook,
    const float* __restrict__ w_after,
    const float* __restrict__ b_after,
    double* __restrict__ g_breaks,
    int* __restrict__ g_win,
    float* __restrict__ g_segcb,
    float* __restrict__ g_segR,
    double* __restrict__ g_segBG,
    double* __restrict__ g_alpha,
    int* __restrict__ g_m)
{
    const int c = blockIdx.x;
    const int lane = threadIdx.x;

    double wp[NQ], bp[NQ], wa[NQ];
    double sw2 = 0.0, swb = 0.0, sb2 = 0.0;
    #pragma unroll
    for (int q = 0; q < NQ; q++) {
        wp[q] = (double)w_pre[c*NQ + q];
        bp[q] = (double)b_pre[c*NQ + q];
        wa[q] = (double)w_after[c*NQ + q];
        sw2 = fma(wp[q], wp[q], sw2);
        swb = fma(wp[q], bp[q], swb);
        sb2 = fma(bp[q], bp[q], sb2);
    }
    const double ba = (double)b_after[c];

    // P,S for the 4 codes this lane owns: k = 4*lane + i
    double P[4], S[4];
    #pragma unroll
    for (int i = 0; i < 4; i++) {
        const int k = 4*lane + i;
        double c2 = 0.0, A = 0.0, Bv = 0.0;
        #pragma unroll
        for (int q = 0; q < NQ; q++) {
            double cv = (double)codebook[k*NQ + q];
            c2 = fma(cv, cv, c2);
            A  = fma(wp[q], cv, A);
            Bv = fma(bp[q], cv, Bv);
        }
        P[i] = c2 - 2.0*Bv;
        S[i] = -2.0*A;
    }

    // winner at x=-inf: max S, tie min P, tie min k
    double bs = S[0], bP = P[0];
    int bk = 4*lane;
    #pragma unroll
    for (int i = 1; i < 4; i++) {
        const int k = 4*lane + i;
        if (S[i] > bs || (S[i] == bs && (P[i] < bP || (P[i] == bP && k < bk)))) {
            bs = S[i]; bP = P[i]; bk = k;
        }
    }
    #pragma unroll
    for (int off = 32; off; off >>= 1) {
        double os = __shfl_xor(bs, off, 64);
        double oP = __shfl_xor(bP, off, 64);
        int    ok = __shfl_xor(bk, off, 64);
        if (os > bs || (os == bs && (oP < bP || (oP == bP && ok < bk)))) {
            bs = os; bP = oP; bk = ok;
        }
    }
    int cur = bk;
    int winners[NK];       // wave-uniform walk, all lanes track the list
    winners[0] = cur;
    int m = 1;

    while (m < NK) {
        const int owner = cur >> 2, slot = cur & 3;
        double Si, Pi;
        { double v = (slot == 0) ? S[0] : (slot == 1) ? S[1] : (slot == 2) ? S[2] : S[3];
          Si = __shfl(v, owner, 64); }
        { double v = (slot == 0) ? P[0] : (slot == 1) ? P[1] : (slot == 2) ? P[2] : P[3];
          Pi = __shfl(v, owner, 64); }

        double cx = DBL_MAX, cs = 0.0;
        int cj = NK;
        #pragma unroll
        for (int i = 0; i < 4; i++) {
            const int k = 4*lane + i;
            if (S[i] < Si) {
                double t = (P[i] - Pi) / (Si - S[i]);
                if (t < cx || (t == cx && (S[i] < cs || (S[i] == cs && k < cj)))) {
                    cx = t; cs = S[i]; cj = k;
                }
            }
        }
        #pragma unroll
        for (int off = 32; off; off >>= 1) {
            double ox = __shfl_xor(cx, off, 64);
            double os = __shfl_xor(cs, off, 64);
            int    oj = __shfl_xor(cj, off, 64);
            if (ox < cx || (ox == cx && (os < cs || (os == cs && oj < cj)))) {
                cx = ox; cs = os; cj = oj;
            }
        }
        if (cx == DBL_MAX) break;
        if (lane == 0) g_breaks[c*NK + m] = cx;
        winners[m] = cj;
        cur = cj;
        m++;
    }
    if (lane == 0) {
        g_m[c] = m;
        g_alpha[c] = sw2;
    }

    // payload: seg i -> {cb row, R, beta, gamma}; winners held in registers
    for (int i = lane; i < m; i += 64) {
        const int j = winners[i];
        if (lane != i % 64) {}          // (indexing is per-lane strided; j valid)
        double c2 = 0.0, A = 0.0, Bv = 0.0, R = ba;
        #pragma unroll
        for (int q = 0; q < NQ; q++) {
            float cf = codebook[j*NQ + q];
            g_segcb[(c*NK + i)*NQ + q] = cf;
            double cv = (double)cf;
            c2 = fma(cv, cv, c2);
            A  = fma(wp[q], cv, A);
            Bv = fma(bp[q], cv, Bv);
            R  = fma(wa[q], cv, R);
        }
        g_segR[c*NK + i] = (float)R;
        g_segBG[(c*NK + i)*2 + 0] = (-2.0*A) + 2.0*swb;     // beta
        g_segBG[(c*NK + i)*2 + 1] = (c2 - 2.0*Bv) + sb2;    // gamma
    }
}

// ---------------------------------------------------------------------------
// Kernel B: per-row binary search + outputs (no fences, no atomics)
// ---------------------------------------------------------------------------
__global__ __launch_bounds__(TPB) void vq_main(
    const float* __restrict__ x,
    const double* __restrict__ g_breaks,
    const float* __restrict__ g_segcb,
    const float* __restrict__ g_segR,
    const double* __restrict__ g_segBG,
    const double* __restrict__ g_alpha,
    const int* __restrict__ g_m,
    float* __restrict__ out,
    double* __restrict__ partial)
{
    __shared__ double s_brk[NK];
    __shared__ float  s_cb[NK][9];     // stride 9: conflict-light divergent reads
    __shared__ float  s_R[NK];
    __shared__ double s_bg[NK][2];
    __shared__ double s_alpha;
    __shared__ double s_part[TPB/64];

    const int tid = threadIdx.x;
    const int gid = blockIdx.x * TPB + tid;
    const int c  = (gid >> 10) & 63;   // block-uniform
    const int b  = gid >> 16;
    const int hw = gid & 1023;

    const int m = g_m[c];
    if (tid == 0) s_alpha = g_alpha[c];
    if (tid < m) {
        s_brk[tid] = (tid == 0) ? -DBL_MAX : g_breaks[c*NK + tid];
        const float4* cb4 = (const float4*)(g_segcb + (c*NK + tid)*NQ);
        float4 c0 = cb4[0], c1 = cb4[1];
        s_cb[tid][0] = c0.x; s_cb[tid][1] = c0.y; s_cb[tid][2] = c0.z; s_cb[tid][3] = c0.w;
        s_cb[tid][4] = c1.x; s_cb[tid][5] = c1.y; s_cb[tid][6] = c1.z; s_cb[tid][7] = c1.w;
        s_R[tid] = g_segR[c*NK + tid];
        const double2 bg = *(const double2*)(g_segBG + (c*NK + tid)*2);
        s_bg[tid][0] = bg.x; s_bg[tid][1] = bg.y;
    }
    __syncthreads();

    const double xv = (double)x[gid];

    // largest seg with s_brk[seg] <= xv
    int lo = 0, hi = m - 1;
    while (lo < hi) {
        int mid = (lo + hi + 1) >> 1;
        if (s_brk[mid] <= xv) lo = mid; else hi = mid - 1;
    }

    const int bq = BIT_OFF + (b*512 + c*8)*1024 + hw;
    #pragma unroll
    for (int q = 0; q < NQ; q++)
        out[bq + q*1024] = s_cb[lo][q];
    out[REC_OFF + gid] = s_R[lo];

    double ksum = fma(xv, fma(xv, s_alpha, s_bg[lo][0]), s_bg[lo][1]);

    #pragma unroll
    for (int off = 32; off; off >>= 1)
        ksum += __shfl_down(ksum, off, 64);
    if ((tid & 63) == 0) s_part[tid >> 6] = ksum;
    __syncthreads();
    if (tid == 0)
        partial[blockIdx.x] = s_part[0] + s_part[1] + s_part[2] + s_part[3];
}

__global__ __launch_bounds__(TPB) void vq_fin(
    const double* __restrict__ partial,
    float* __restrict__ out)
{
    double s = 0.0;
    for (int i = threadIdx.x; i < NBLK; i += TPB) s += partial[i];
    #pragma unroll
    for (int off = 32; off; off >>= 1)
        s += __shfl_down(s, off, 64);
    __shared__ double sp[TPB/64];
    if ((threadIdx.x & 63) == 0) sp[threadIdx.x >> 6] = s;
    __syncthreads();
    if (threadIdx.x == 0) {
        double m = (sp[0] + sp[1] + sp[2] + sp[3]) / (double)(NROWS * NQ);
        out[0] = (float)(1.25 * m);
    }
}

extern "C" void kernel_launch(void* const* d_in, const int* in_sizes, int n_in,
                              void* d_out, int out_size, void* d_ws, size_t ws_size,
                              hipStream_t stream) {
    const float* x        = (const float*)d_in[0];
    const float* w_pre    = (const float*)d_in[1];
    const float* b_pre    = (const float*)d_in[2];
    const float* codebook = (const float*)d_in[3];
    const float* w_after  = (const float*)d_in[4];
    const float* b_after  = (const float*)d_in[5];
    float* out = (float*)d_out;

    vq_envelope<<<NC, 64, 0, stream>>>(w_pre, b_pre, codebook, w_after, b_after,
                                       WS_BREAKS(d_ws), WS_WIN(d_ws), WS_SEGCB(d_ws),
                                       WS_SEGR(d_ws), WS_SEGBG(d_ws), WS_ALPHA(d_ws),
                                       WS_M(d_ws));
    vq_main<<<NBLK, TPB, 0, stream>>>(x, WS_BREAKS(d_ws), WS_SEGCB(d_ws),
                                      WS_SEGR(d_ws), WS_SEGBG(d_ws), WS_ALPHA(d_ws),
                                      WS_M(d_ws), out, WS_PART(d_ws));
    vq_fin<<<1, TPB, 0, stream>>>(WS_PART(d_ws), out);
}

// Round 6
// 27.543 us; speedup vs baseline: 3.4836x; 1.1048x over previous
//
#include <hip/hip_runtime.h>
#include <float.h>

#define NB 8
#define NC 64
#define NH 32
#define NW 32
#define NQ 8
#define NK 256
#define NROWS (NB*NC*NH*NW)      // 524288
#define TPB 256
#define RPB 1024                 // rows per vq_main block (one (b,c) plane)
#define NBLK2 (NROWS/RPB)        // 512
#define BIT_OFF 1
#define REC_OFF (1 + NROWS*NQ)

// ws layout (bytes):
//  g_breaks: double[64][256]     @ 0        (128 KiB)
//  g_segcb:  float [64][256][8]  @ 196608   (512 KiB)
//  g_segR:   float [64][256]     @ 720896   ( 64 KiB)
//  g_segBG:  double[64][256][2]  @ 786432   (256 KiB)
//  g_alpha:  double[64]          @ 1048576
//  g_m:      int[64]             @ 1049088
//  partial:  double[512]         @ 1049856
#define WS_BREAKS(ws) ((double*)(ws))
#define WS_SEGCB(ws)  ((float*)((char*)(ws) + 196608))
#define WS_SEGR(ws)   ((float*)((char*)(ws) + 720896))
#define WS_SEGBG(ws)  ((double*)((char*)(ws) + 786432))
#define WS_ALPHA(ws)  ((double*)((char*)(ws) + 1048576))
#define WS_M(ws)      ((int*)((char*)(ws) + 1049088))
#define WS_PART(ws)   ((double*)((char*)(ws) + 1049856))

// ---------------------------------------------------------------------------
// Kernel A: one wave per channel; lower envelope of d_k(x) = P[k] + x*S[k];
// per-segment payload {break, cb row, R, beta, gamma}. f64 semantics identical
// to the verified R3/R5 kernels (same ops, same lex tie-breaks).
// ---------------------------------------------------------------------------
__global__ __launch_bounds__(64) void vq_envelope(
    const float* __restrict__ w_pre,
    const float* __restrict__ b_pre,
    const float* __restrict__ codebook,
    const float* __restrict__ w_after,
    const float* __restrict__ b_after,
    double* __restrict__ g_breaks,
    float* __restrict__ g_segcb,
    float* __restrict__ g_segR,
    double* __restrict__ g_segBG,
    double* __restrict__ g_alpha,
    int* __restrict__ g_m)
{
    __shared__ double2 s_PS[NK];   // {P,S} per code — broadcast reads in walk
    __shared__ int     s_win[NK];  // winner code per segment (no scratch!)

    const int c = blockIdx.x;
    const int lane = threadIdx.x;

    double wp[NQ], bp[NQ], wa[NQ];
    double sw2 = 0.0, swb = 0.0, sb2 = 0.0;
    #pragma unroll
    for (int q = 0; q < NQ; q++) {
        wp[q] = (double)w_pre[c*NQ + q];
        bp[q] = (double)b_pre[c*NQ + q];
        wa[q] = (double)w_after[c*NQ + q];
        sw2 = fma(wp[q], wp[q], sw2);
        swb = fma(wp[q], bp[q], swb);
        sb2 = fma(bp[q], bp[q], sb2);
    }
    const double ba = (double)b_after[c];

    // P,S for the 4 codes this lane owns: k = 4*lane + i (regs + LDS copy)
    double P[4], S[4];
    #pragma unroll
    for (int i = 0; i < 4; i++) {
        const int k = 4*lane + i;
        double c2 = 0.0, A = 0.0, Bv = 0.0;
        #pragma unroll
        for (int q = 0; q < NQ; q++) {
            double cv = (double)codebook[k*NQ + q];
            c2 = fma(cv, cv, c2);
            A  = fma(wp[q], cv, A);
            Bv = fma(bp[q], cv, Bv);
        }
        P[i] = c2 - 2.0*Bv;
        S[i] = -2.0*A;
        s_PS[k] = make_double2(P[i], S[i]);
    }

    // winner at x=-inf: max S, tie min P, tie min k
    double bs = S[0], bP = P[0];
    int bk = 4*lane;
    #pragma unroll
    for (int i = 1; i < 4; i++) {
        const int k = 4*lane + i;
        if (S[i] > bs || (S[i] == bs && (P[i] < bP || (P[i] == bP && k < bk)))) {
            bs = S[i]; bP = P[i]; bk = k;
        }
    }
    #pragma unroll
    for (int off = 32; off; off >>= 1) {
        double os = __shfl_xor(bs, off, 64);
        double oP = __shfl_xor(bP, off, 64);
        int    ok = __shfl_xor(bk, off, 64);
        if (os > bs || (os == bs && (oP < bP || (oP == bP && ok < bk)))) {
            bs = os; bP = oP; bk = ok;
        }
    }
    int cur = bk;
    if (lane == 0) s_win[0] = cur;
    int m = 1;

    while (m < NK) {
        const double2 psi = s_PS[cur];     // wave-uniform broadcast (b128)
        const double Pi = psi.x, Si = psi.y;

        double cx = DBL_MAX, cs = 0.0;
        int cj = NK;
        #pragma unroll
        for (int i = 0; i < 4; i++) {
            const int k = 4*lane + i;
            if (S[i] < Si) {
                double t = (P[i] - Pi) / (Si - S[i]);
                if (t < cx || (t == cx && (S[i] < cs || (S[i] == cs && k < cj)))) {
                    cx = t; cs = S[i]; cj = k;
                }
            }
        }
        #pragma unroll
        for (int off = 32; off; off >>= 1) {
            double ox = __shfl_xor(cx, off, 64);
            double os = __shfl_xor(cs, off, 64);
            int    oj = __shfl_xor(cj, off, 64);
            if (ox < cx || (ox == cx && (os < cs || (os == cs && oj < cj)))) {
                cx = ox; cs = os; cj = oj;
            }
        }
        if (cx == DBL_MAX) break;
        if (lane == 0) {
            g_breaks[c*NK + m] = cx;
            s_win[m] = cj;
        }
        cur = cj;
        m++;
    }
    if (lane == 0) {
        g_m[c] = m;
        g_alpha[c] = sw2;
    }

    // payload: seg i -> {cb row, R, beta, gamma}
    for (int i = lane; i < m; i += 64) {
        const int j = s_win[i];
        double c2 = 0.0, A = 0.0, Bv = 0.0, R = ba;
        #pragma unroll
        for (int q = 0; q < NQ; q++) {
            float cf = codebook[j*NQ + q];
            g_segcb[(c*NK + i)*NQ + q] = cf;
            double cv = (double)cf;
            c2 = fma(cv, cv, c2);
            A  = fma(wp[q], cv, A);
            Bv = fma(bp[q], cv, Bv);
            R  = fma(wa[q], cv, R);
        }
        g_segR[c*NK + i] = (float)R;
        g_segBG[(c*NK + i)*2 + 0] = (-2.0*A) + 2.0*swb;     // beta
        g_segBG[(c*NK + i)*2 + 1] = (c2 - 2.0*Bv) + sb2;    // gamma
    }
}

// ---------------------------------------------------------------------------
// Kernel B: 512 blocks, 1024 rows each (one (b,c) plane); 4 rows per thread.
// ---------------------------------------------------------------------------
__global__ __launch_bounds__(TPB) void vq_main(
    const float* __restrict__ x,
    const double* __restrict__ g_breaks,
    const float* __restrict__ g_segcb,
    const float* __restrict__ g_segR,
    const double* __restrict__ g_segBG,
    const double* __restrict__ g_alpha,
    const int* __restrict__ g_m,
    float* __restrict__ out,
    double* __restrict__ partial)
{
    __shared__ double s_brk[NK];
    __shared__ float  s_cb[NK][9];     // stride 9: conflict-light divergent reads
    __shared__ float  s_R[NK];
    __shared__ double s_bg[NK][2];
    __shared__ double s_alpha;
    __shared__ double s_part[TPB/64];

    const int tid = threadIdx.x;
    const int bc = blockIdx.x;         // = b*64 + c
    const int b = bc >> 6;
    const int c = bc & 63;
    const int rowbase = bc * RPB;      // = b*65536 + c*1024

    const int m = g_m[c];
    if (tid == 0) s_alpha = g_alpha[c];
    if (tid < m) {
        s_brk[tid] = (tid == 0) ? -DBL_MAX : g_breaks[c*NK + tid];
        const float4* cb4 = (const float4*)(g_segcb + (c*NK + tid)*NQ);
        float4 c0 = cb4[0], c1 = cb4[1];
        s_cb[tid][0] = c0.x; s_cb[tid][1] = c0.y; s_cb[tid][2] = c0.z; s_cb[tid][3] = c0.w;
        s_cb[tid][4] = c1.x; s_cb[tid][5] = c1.y; s_cb[tid][6] = c1.z; s_cb[tid][7] = c1.w;
        s_R[tid] = g_segR[c*NK + tid];
        const double2 bg = *(const double2*)(g_segBG + (c*NK + tid)*2);
        s_bg[tid][0] = bg.x; s_bg[tid][1] = bg.y;
    }
    __syncthreads();

    const double alpha = s_alpha;
    const int bq0 = BIT_OFF + (b*512 + c*8)*1024;

    double ktot = 0.0;
    #pragma unroll
    for (int r = 0; r < 4; r++) {
        const int hw  = r*256 + tid;
        const int gid = rowbase + hw;
        const double xv = (double)x[gid];

        int lo = 0, hi = m - 1;
        while (lo < hi) {                       // block-uniform trip count
            int mid = (lo + hi + 1) >> 1;
            if (s_brk[mid] <= xv) lo = mid; else hi = mid - 1;
        }

        #pragma unroll
        for (int q = 0; q < NQ; q++)
            out[bq0 + q*1024 + hw] = s_cb[lo][q];
        out[REC_OFF + gid] = s_R[lo];

        ktot += fma(xv, fma(xv, alpha, s_bg[lo][0]), s_bg[lo][1]);
    }

    #pragma unroll
    for (int off = 32; off; off >>= 1)
        ktot += __shfl_down(ktot, off, 64);
    if ((tid & 63) == 0) s_part[tid >> 6] = ktot;
    __syncthreads();
    if (tid == 0)
        partial[blockIdx.x] = s_part[0] + s_part[1] + s_part[2] + s_part[3];
}

__global__ __launch_bounds__(TPB) void vq_fin(
    const double* __restrict__ partial,
    float* __restrict__ out)
{
    double s = 0.0;
    for (int i = threadIdx.x; i < NBLK2; i += TPB) s += partial[i];
    #pragma unroll
    for (int off = 32; off; off >>= 1)
        s += __shfl_down(s, off, 64);
    __shared__ double sp[TPB/64];
    if ((threadIdx.x & 63) == 0) sp[threadIdx.x >> 6] = s;
    __syncthreads();
    if (threadIdx.x == 0) {
        double m = (sp[0] + sp[1] + sp[2] + sp[3]) / (double)(NROWS * NQ);
        out[0] = (float)(1.25 * m);
    }
}

extern "C" void kernel_launch(void* const* d_in, const int* in_sizes, int n_in,
                              void* d_out, int out_size, void* d_ws, size_t ws_size,
                              hipStream_t stream) {
    const float* x        = (const float*)d_in[0];
    const float* w_pre    = (const float*)d_in[1];
    const float* b_pre    = (const float*)d_in[2];
    const float* codebook = (const float*)d_in[3];
    const float* w_after  = (const float*)d_in[4];
    const float* b_after  = (const float*)d_in[5];
    float* out = (float*)d_out;

    vq_envelope<<<NC, 64, 0, stream>>>(w_pre, b_pre, codebook, w_after, b_after,
                                       WS_BREAKS(d_ws), WS_SEGCB(d_ws),
                                       WS_SEGR(d_ws), WS_SEGBG(d_ws), WS_ALPHA(d_ws),
                                       WS_M(d_ws));
    vq_main<<<NBLK2, TPB, 0, stream>>>(x, WS_BREAKS(d_ws), WS_SEGCB(d_ws),
                                       WS_SEGR(d_ws), WS_SEGBG(d_ws), WS_ALPHA(d_ws),
                                       WS_M(d_ws), out, WS_PART(d_ws));
    vq_fin<<<1, TPB, 0, stream>>>(WS_PART(d_ws), out);
}